// Round 10
// baseline (405.879 us; speedup 1.0000x reference)
//
#include <hip/hip_runtime.h>
#include <hip/hip_bf16.h>

typedef unsigned short u16;
typedef unsigned int u32;
typedef unsigned long long u64;
typedef __attribute__((ext_vector_type(8))) short s16x8;
typedef __attribute__((ext_vector_type(4))) float f32x4;
typedef __attribute__((ext_vector_type(16))) float f32x16;

#define SCL 0.1803368867f   // 0.125 * log2(e): exp(s/8) = 2^(s*SCL)

#if __has_builtin(__builtin_amdgcn_exp2f)
#define EXP2(x) __builtin_amdgcn_exp2f(x)
#else
#define EXP2(x) exp2f(x)
#endif

__device__ __forceinline__ float bf2f(u16 v){ u32 u = ((u32)v)<<16; return __builtin_bit_cast(float,u); }
__device__ __forceinline__ u16 f2bf(float f){
  u32 u = __builtin_bit_cast(u32,f);
  u += 0x7fff + ((u>>16)&1);
  return (u16)(u>>16);
}
__device__ __forceinline__ u32 pkbf(float a, float b){   // pack 2 bf16
  u32 ua = __builtin_bit_cast(u32,a) + 0x8000u;
  u32 ub = __builtin_bit_cast(u32,b) + 0x8000u;
  return (ua>>16) | (ub & 0xFFFF0000u);
}
// async global->LDS, 16B per lane; lds_u MUST be wave-uniform (HW adds lane*16)
__device__ __forceinline__ void glds16(const u16* g, const u16* lds_u){
  __builtin_amdgcn_global_load_lds(
      (const __attribute__((address_space(1))) void*)(u64)g,
      (__attribute__((address_space(3))) void*)(u32)(u64)lds_u,
      16, 0, 0);
}
__device__ __forceinline__ f32x4 mfma16(s16x8 a, s16x8 b, f32x4 c){
  return __builtin_amdgcn_mfma_f32_16x16x32_bf16(a,b,c,0,0,0);
}
__device__ __forceinline__ f32x16 mfma32(s16x8 a, s16x8 b, f32x16 c){
  return __builtin_amdgcn_mfma_f32_32x32x16_bf16(a,b,c,0,0,0);
}

// ---------------------------------------------------------------------------
// dtype probe (validated rounds 2-9)
// ---------------------------------------------------------------------------
__global__ __launch_bounds__(256) void detect_dtype(const u16* __restrict__ x, u32* __restrict__ flag){
  __shared__ int cnt;
  if (threadIdx.x==0) cnt = 0;
  __syncthreads();
  int local = 0;
  for (int i = threadIdx.x; i < 4096; i += 256){
    u16 v = x[2*i];
    int e = (v>>7)&0xFF;
    if (e >= 140 || e <= 100) local++;
  }
  atomicAdd(&cnt, local);
  __syncthreads();
  if (threadIdx.x==0) *flag = (cnt > 1024) ? 1u : 0u;
}

struct CvtArgs { const void* src[10]; u16* dst[10]; int n[10]; };

__global__ __launch_bounds__(256) void convert_inputs(CvtArgs a, const u32* __restrict__ flag){
  const int which = blockIdx.y;
  const int n = a.n[which];
  const int base = blockIdx.x*2048 + threadIdx.x;
  if (base >= n) return;
  u16* dst = a.dst[which];
  if (*flag){
    const float* s = (const float*)a.src[which];
    #pragma unroll
    for (int j=0;j<8;j++){ int i = base + j*256; if (i<n) dst[i] = f2bf(s[i]); }
  } else {
    const u16* s = (const u16*)a.src[which];
    #pragma unroll
    for (int j=0;j<8;j++){ int i = base + j*256; if (i<n) dst[i] = s[i]; }
  }
}

// ---------------------------------------------------------------------------
// Fused convert+transpose of x: xT[b][c][s] = cvt(x[b][s][c]).  Grid (32,16,2).
// ---------------------------------------------------------------------------
__global__ __launch_bounds__(256) void transpose_x(
    const void* __restrict__ src, const u32* __restrict__ flag, u16* __restrict__ dst)
{
  __shared__ u16 T[64][72];
  const int s0 = blockIdx.x*64, c0 = blockIdx.y*64, b = blockIdx.z;
  const int t = threadIdx.x;
  const int r = t>>2, cc = (t&3)*16;
  const long off = ((long)(b*2048 + s0 + r))*1024 + c0 + cc;
  if (*flag){
    const float* p = (const float*)src + off;
    #pragma unroll
    for (int j=0;j<16;j++) T[r][cc+j] = f2bf(p[j]);
  } else {
    const u16* p = (const u16*)src + off;
    *(s16x8*)&T[r][cc]   = *(const s16x8*)p;
    *(s16x8*)&T[r][cc+8] = *(const s16x8*)(p+8);
  }
  __syncthreads();
  {
    const int orow = t&63, oc = (t>>6)*16;
    u16 tmp[16];
    #pragma unroll
    for (int j=0;j<16;j++) tmp[j] = T[oc+j][orow];
    u16* q = dst + (long)b*2097152 + (long)(c0+orow)*2048 + s0 + oc;
    *(s16x8*)q     = *(s16x8*)&tmp[0];
    *(s16x8*)(q+8) = *(s16x8*)&tmp[8];
  }
}

// sv partials from UNSCALED v inside qkv
__global__ __launch_bounds__(256) void rowsum_part(const u16* __restrict__ qkv, float* __restrict__ svp){
  const int c = blockIdx.x*256 + threadIdx.x;   // 0..2047 = b*1024 + cc
  const int b = c>>10, cc = c&1023;
  const int tz = blockIdx.y;
  const u16* p = qkv + ((long)(b*2048 + tz*256))*3072 + 2048 + cc;
  float s = 0.f;
  #pragma unroll 8
  for (int i=0;i<256;i++) s += bf2f(p[(long)i*3072]);
  svp[tz*2048 + c] = s;
}
__global__ __launch_bounds__(256) void rowsum_fin(const float* __restrict__ svp, float* __restrict__ sv){
  const int c = blockIdx.x*256 + threadIdx.x;
  float s = 0.f;
  #pragma unroll
  for (int z=0;z<8;z++) s += svp[z*2048 + c];
  sv[c] = s;
}

// ---------------------------------------------------------------------------
// NT GEMM, BM=128 x BN tile, BK=32, double-buffered LDS + global_load_lds(16B).
// (round-5/7 version — proven)
// ---------------------------------------------------------------------------
template<int BN, int BMODE, bool DYN, bool QS>
__global__ __launch_bounds__(256) void gemm_t(
    const u16* __restrict__ A, const u16* __restrict__ B,
    const u16* __restrict__ bias, const float* __restrict__ r1col,
    const u32* __restrict__ dflag, void* __restrict__ C,
    int K, int lda, int ldb, int ldc,
    long aBatch, long bBatch, long cBatch)
{
  constexpr int BM = 128;
  constexpr int ACH = BM/64, BCH = BN/64;
  constexpr int MI = (BN==128) ? 4 : 2;
  __shared__ u16 As[2][BM*32];
  __shared__ u16 Bs[2][BN*32];
  const int t = threadIdx.x, w = t>>6, quad = (t&63)>>4, l16 = t&15;
  const int z = blockIdx.z;
  const int m0 = blockIdx.x*BM, n0 = blockIdx.y*BN;
  const u16* Ag = A + (long)z*aBatch + (long)m0*lda;
  const u16* Bg = B + (long)z*bBatch + (long)n0*ldb;
  const int wm = (BN==128) ? (w>>1)*64 : w*32;
  const int wn = (BN==128) ? (w&1)*64 : 0;

  auto stage = [&](int buf, int k0){
    #pragma unroll
    for (int i=0;i<ACH;i++){
      const int chunk = i*256 + t;
      glds16(Ag + (long)(chunk>>2)*lda + k0 + (chunk&3)*8, &As[buf][(i*256 + w*64)*8]);
    }
    #pragma unroll
    for (int i=0;i<BCH;i++){
      const int chunk = i*256 + t;
      glds16(Bg + (long)(chunk>>2)*ldb + k0 + (chunk&3)*8, &Bs[buf][(i*256 + w*64)*8]);
    }
  };

  f32x4 acc[MI][4];
  #pragma unroll
  for (int i=0;i<MI;i++)
    #pragma unroll
    for (int j=0;j<4;j++) acc[i][j] = (f32x4){0.f,0.f,0.f,0.f};

  stage(0, 0);
  const int nk = K>>5;
  for (int kt=0; kt<nk; ++kt){
    __syncthreads();
    if (kt+1 < nk) stage((kt+1)&1, (kt+1)<<5);
    const u16* as = As[kt&1];
    const u16* bs = Bs[kt&1];
    s16x8 a[MI], bb[4];
    #pragma unroll
    for (int i=0;i<MI;i++) a[i] = *(const s16x8*)&as[(wm + i*16 + l16)*32 + quad*8];
    #pragma unroll
    for (int j=0;j<4;j++)  bb[j]= *(const s16x8*)&bs[(wn + j*16 + l16)*32 + quad*8];
    #pragma unroll
    for (int i=0;i<MI;i++)
      #pragma unroll
      for (int j=0;j<4;j++)
        acc[i][j] = mfma16(a[i], bb[j], acc[i][j]);
  }

  bool f32o = false;
  if (DYN) f32o = (*dflag != 0);
  #pragma unroll
  for (int i=0;i<MI;i++){
    #pragma unroll
    for (int j=0;j<4;j++){
      const int col = n0 + wn + j*16 + l16;
      #pragma unroll
      for (int r=0;r<4;r++){
        const int row = m0 + wm + i*16 + quad*4 + r;
        float vv = acc[i][j][r];
        if (BMODE==1) vv += bf2f(bias[row]);
        if (BMODE==2) vv += bf2f(bias[col]);
        if (BMODE==3) vv += bf2f(bias[row]) * r1col[z*1024 + col];
        if (QS){ if (col < 1024) vv *= SCL; }
        const long idx = (long)z*cBatch + (long)row*ldc + col;
        if (DYN && f32o) ((float*)C)[idx] = vv;
        else             ((u16*)C)[idx]   = f2bf(vv);
      }
    }
  }
}

// ---------------------------------------------------------------------------
// Fused softmax-denominator + V-scale-transpose (R9 version — proven).
// ---------------------------------------------------------------------------
__global__ __launch_bounds__(256) void attn_stats(const u16* __restrict__ qkv, u16* __restrict__ VtG){
  __shared__ u16 Qs[64][68];
  __shared__ u16 Ks[64][68];
  __shared__ float red[2][64];
  __shared__ float ilv[64];
  const int q0 = blockIdx.x*64, bh = blockIdx.y, b = bh>>4, h = bh&15;
  const int t = threadIdx.x, w = t>>6, l32 = t&31, half = (t&63)>>5;
  const int wq = w>>1, wk = w&1;
  {
    const int r = t>>2, cc = (t&3)*16;
    const u16* p = &qkv[((long)(b*2048 + q0 + r))*3072 + h*64 + cc];
    *(s16x8*)&Qs[r][cc]   = *(const s16x8*)p;
    *(s16x8*)&Qs[r][cc+8] = *(const s16x8*)(p+8);
  }
  __syncthreads();
  s16x8 aq[4];
  #pragma unroll
  for (int u=0;u<4;u++) aq[u] = *(s16x8*)&Qs[wq*32 + l32][u*16 + half*8];
  float lp[16];
  #pragma unroll
  for (int r=0;r<16;r++) lp[r] = 0.f;

  for (int kc=0; kc<2048; kc+=64){
    __syncthreads();
    {
      const int r = t>>2, cc = (t&3)*16;
      const u16* p = &qkv[((long)(b*2048 + kc + r))*3072 + 1024 + h*64 + cc];
      *(s16x8*)&Ks[r][cc]   = *(const s16x8*)p;
      *(s16x8*)&Ks[r][cc+8] = *(const s16x8*)(p+8);
    }
    __syncthreads();
    s16x8 kb[4];
    #pragma unroll
    for (int u=0;u<4;u++) kb[u] = *(s16x8*)&Ks[wk*32 + l32][u*16 + half*8];
    f32x16 acc = {};
    #pragma unroll
    for (int u=0;u<4;u++) acc = mfma32(aq[u], kb[u], acc);
    #pragma unroll
    for (int r=0;r<16;r++) lp[r] += EXP2(acc[r]);
  }
  #pragma unroll
  for (int off=1; off<32; off<<=1)
    #pragma unroll
    for (int r=0;r<16;r++) lp[r] += __shfl_xor(lp[r], off);
  if (l32 == 0){
    #pragma unroll
    for (int r=0;r<16;r++)
      red[wk][wq*32 + 4*half + (r&3) + 8*(r>>2)] = lp[r];
  }
  __syncthreads();
  if (t < 64) ilv[t] = 1.f / (red[0][t] + red[1][t]);
  __syncthreads();
  // ---- fused V scale+transpose through Qs (dead after aq) ----
  {
    const int r = t>>2, cc = (t&3)*16;
    const u16* p = &qkv[((long)(b*2048 + q0 + r))*3072 + 2048 + h*64 + cc];
    const float sc = ilv[r];
    s16x8 v0 = *(const s16x8*)p, v1 = *(const s16x8*)(p+8);
    #pragma unroll
    for (int j=0;j<8;j++){
      Qs[r][cc+j]   = f2bf(bf2f((u16)v0[j])*sc);
      Qs[r][cc+8+j] = f2bf(bf2f((u16)v1[j])*sc);
    }
  }
  __syncthreads();
  {
    const int orow = t&63, oc = (t>>6)*16;
    u16 tmp[16];
    #pragma unroll
    for (int j=0;j<16;j++) tmp[j] = Qs[oc+j][orow];
    u16* q = VtG + (long)b*2097152 + (long)(h*64+orow)*2048 + q0 + oc;
    *(s16x8*)q     = *(s16x8*)&tmp[0];
    *(s16x8*)(q+8) = *(s16x8*)&tmp[8];
  }
}

// ---------------------------------------------------------------------------
// pv-direct: Mt[b, h*64+d, k] = sum_q exp2(q'.k) * vtilde[d,q].
// Q/V/K fragments are pure row-reads -> loaded DIRECTLY from global into regs
// (L2/L3-hot, deep prefetch, no barriers). Only P^T goes through LDS.
// 2 barriers/iter (was 3), no staging writes.  LDS: Ps 8.7 KB + 28 KB dead pad
// to pin capacity at exactly 4 blocks/CU (R9 lesson: excess capacity -> CP
// packing imbalance).  Grid (32, 32), block 256.
// ---------------------------------------------------------------------------
__global__ __launch_bounds__(256) void attn_pv(
    const u16* __restrict__ qkv, const u16* __restrict__ VtG, u16* __restrict__ Mt)
{
  __shared__ u16 Ps[64][68];
  __shared__ u16 pad[14336];   // capacity pin: total LDS 37.4 KB -> 4 blocks/CU
  const int k0 = blockIdx.x*64, bh = blockIdx.y, b = bh>>4, h = bh&15;
  const int t = threadIdx.x, w = t>>6, l32 = t&31, half = (t&63)>>5;
  const int wr = w>>1, wk = w&1;
  if (Mt == nullptr) ((volatile u16*)pad)[t] = 0;   // keep pad allocated

  // K fragments: rows k0+wk*32+l32, head h, cols u*16+half*8  (loaded once)
  const u16* kbase = qkv + ((long)(b*2048 + k0 + wk*32 + l32))*3072 + 1024 + h*64 + half*8;
  s16x8 kb[4];
  #pragma unroll
  for (int u=0;u<4;u++) kb[u] = *(const s16x8*)(kbase + u*16);

  const u16* qbase = qkv + ((long)(b*2048 + wr*32 + l32))*3072 + h*64 + half*8;
  const u16* vbase = VtG + ((long)(b*1024 + h*64 + wr*32 + l32))*2048 + half*8;

  s16x8 aq[4], av[4];
  #pragma unroll
  for (int u=0;u<4;u++) aq[u] = *(const s16x8*)(qbase + u*16);
  #pragma unroll
  for (int u=0;u<4;u++) av[u] = *(const s16x8*)(vbase + u*16);

  f32x16 accM = {};
  const int kcol = wk*32 + l32;
  for (int i=0; i<32; i++){
    // QK(i) from regs
    f32x16 acc = {};
    #pragma unroll
    for (int u=0;u<4;u++) acc = mfma32(aq[u], kb[u], acc);
    // prefetch aq(i+1) — regs free after the mfma reads
    if (i < 31){
      const u16* qn = qbase + (long)(i+1)*64*3072;
      #pragma unroll
      for (int u=0;u<4;u++) aq[u] = *(const s16x8*)(qn + u*16);
    }
    // exp + pack BEFORE the barrier (keeps the write window tiny)
    u64 pk[4];
    #pragma unroll
    for (int g=0; g<4; g++){
      float p0 = EXP2(acc[4*g+0]);
      float p1 = EXP2(acc[4*g+1]);
      float p2 = EXP2(acc[4*g+2]);
      float p3 = EXP2(acc[4*g+3]);
      pk[g] = (u64)pkbf(p0,p1) | ((u64)pkbf(p2,p3) << 32);
    }
    __syncthreads();   // barrier A: PV(i-1) Ps reads complete in all waves
    #pragma unroll
    for (int g=0; g<4; g++)
      *(u64*)&Ps[kcol][wr*32 + 8*g + 4*half] = pk[g];
    __syncthreads();   // barrier B: Ps(i) visible
    // PV(i) from av regs + Ps
    s16x8 bp[4];
    #pragma unroll
    for (int u=0;u<4;u++) bp[u] = *(s16x8*)&Ps[wk*32 + l32][u*16 + half*8];
    #pragma unroll
    for (int u=0;u<4;u++) accM = mfma32(av[u], bp[u], accM);
    // prefetch av(i+1)
    if (i < 31){
      const u16* vn = vbase + (i+1)*64;
      #pragma unroll
      for (int u=0;u<4;u++) av[u] = *(const s16x8*)(vn + u*16);
    }
  }
  #pragma unroll
  for (int r=0;r<16;r++){
    const int d = wr*32 + 4*half + (r&3) + 8*(r>>2);
    const int k = k0 + wk*32 + l32;
    Mt[((long)(b*1024 + h*64 + d))*2048 + k] = f2bf(accM[r]);
  }
}

extern "C" void kernel_launch(void* const* d_in, const int* in_sizes, int n_in,
                              void* d_out, int out_size, void* d_ws, size_t ws_size,
                              hipStream_t stream)
{
  (void)n_in; (void)out_size; (void)ws_size;
  char* ws = (char*)d_ws;
  u32*  dflag = (u32*)ws;            ws += 64;
  u16*  whc   = (u16*)ws;            ws += (size_t)8388608;
  u16*  wqkvc = (u16*)ws;            ws += (size_t)6291456;
  u16*  woc   = (u16*)ws;            ws += (size_t)8388608;
  u16*  bhc   = (u16*)ws;            ws += 4096;
  u16*  bqkvc = (u16*)ws;            ws += 8192;
  u16*  boc   = (u16*)ws;            ws += 4096;
  u16*  xT    = (u16*)ws;            ws += (size_t)8388608;
  u16*  xh    = (u16*)ws;            ws += (size_t)8388608;
  u16*  qkvb  = (u16*)ws;            ws += (size_t)25165824;
  u16*  VtG   = (u16*)ws;            ws += (size_t)8388608;
  u16*  Mt    = (u16*)ws;            ws += (size_t)8388608;
  float* svp  = (float*)ws;          ws += (size_t)65536;
  float* sv   = (float*)ws;          ws += 8192;

  // 0) probe dtype + canonicalize weight/bias inputs to bf16 (x handled by transpose_x)
  detect_dtype<<<1,256,0,stream>>>((const u16*)d_in[0], dflag);
  CvtArgs ca;
  const void* srcs[10] = {d_in[1], d_in[2], d_in[3], d_in[4], d_in[5],
                          d_in[6], d_in[7], d_in[8], d_in[9], d_in[10]};
  u16* dsts[10] = {whc, bhc, wqkvc, bqkvc, wqkvc+1048576, bqkvc+1024,
                   wqkvc+2097152, bqkvc+2048, woc, boc};
  const int ns[10] = {in_sizes[1], in_sizes[2], in_sizes[3], in_sizes[4], in_sizes[5],
                      in_sizes[6], in_sizes[7], in_sizes[8], in_sizes[9], in_sizes[10]};
  for (int i=0;i<10;i++){ ca.src[i]=srcs[i]; ca.dst[i]=dsts[i]; ca.n[i]=ns[i]; }
  convert_inputs<<<dim3(2048,10),256,0,stream>>>(ca, dflag);

  const long S2M = 2097152L;   // 2048*1024

  // 1) xT[b,c,s] = cvt(x[b,s,c])^T   (fused convert+transpose)
  transpose_x<<<dim3(32,16,2),256,0,stream>>>(d_in[0], dflag, xT);

  // 2) xh = w_hseq @ xT^T + b_hseq   (NT, row bias)
  gemm_t<64,1,false,false><<<dim3(16,16,2),256,0,stream>>>(whc, xT, bhc, nullptr, dflag, xh,
      2048, 2048, 2048, 1024, 0L, S2M, S2M);

  // 3) qkv = xh @ Wqkv^T + bqkv; q-columns pre-scaled by SCL   (NT, col bias)
  gemm_t<128,2,false,true><<<dim3(16,24,2),256,0,stream>>>(xh, wqkvc, bqkvc, nullptr, dflag, qkvb,
      1024, 1024, 1024, 3072, S2M, 0L, (long)2048*3072);

  // 4) sv[b,c] = sum_t v[b,t,c]
  rowsum_part<<<dim3(8,8),256,0,stream>>>(qkvb, svp);
  rowsum_fin<<<8,256,0,stream>>>(svp, sv);

  // 5) softmax denominators + fused V scale-transpose -> VtG
  attn_stats<<<dim3(32,32),256,0,stream>>>(qkvb, VtG);

  // 6) Mt = (attn^T @ v)^T   (pv-direct: reg fragments, 2 barriers/iter)
  attn_pv<<<dim3(32,32),256,0,stream>>>(qkvb, VtG, Mt);

  // 7) out = w_oseq @ Mt^T + b_oseq (x) sv   (NT, rank-1 bias, dyn dtype)
  gemm_t<64,3,true,false><<<dim3(16,16,2),256,0,stream>>>(woc, Mt, boc, sv, dflag, d_out,
      2048, 2048, 2048, 1024, 0L, S2M, S2M);
}

// Round 11
// 345.305 us; speedup vs baseline: 1.1754x; 1.1754x over previous
//
#include <hip/hip_runtime.h>
#include <hip/hip_bf16.h>

typedef unsigned short u16;
typedef unsigned int u32;
typedef unsigned long long u64;
typedef __attribute__((ext_vector_type(8))) short s16x8;
typedef __attribute__((ext_vector_type(4))) float f32x4;
typedef __attribute__((ext_vector_type(16))) float f32x16;

#define SCL 0.1803368867f   // 0.125 * log2(e): exp(s/8) = 2^(s*SCL)

#if __has_builtin(__builtin_amdgcn_exp2f)
#define EXP2(x) __builtin_amdgcn_exp2f(x)
#else
#define EXP2(x) exp2f(x)
#endif

__device__ __forceinline__ float bf2f(u16 v){ u32 u = ((u32)v)<<16; return __builtin_bit_cast(float,u); }
__device__ __forceinline__ u16 f2bf(float f){
  u32 u = __builtin_bit_cast(u32,f);
  u += 0x7fff + ((u>>16)&1);
  return (u16)(u>>16);
}
__device__ __forceinline__ u32 pkbf(float a, float b){   // pack 2 bf16
  u32 ua = __builtin_bit_cast(u32,a) + 0x8000u;
  u32 ub = __builtin_bit_cast(u32,b) + 0x8000u;
  return (ua>>16) | (ub & 0xFFFF0000u);
}
// async global->LDS, 16B per lane; lds_u MUST be wave-uniform (HW adds lane*16)
__device__ __forceinline__ void glds16(const u16* g, const u16* lds_u){
  __builtin_amdgcn_global_load_lds(
      (const __attribute__((address_space(1))) void*)(u64)g,
      (__attribute__((address_space(3))) void*)(u32)(u64)lds_u,
      16, 0, 0);
}
__device__ __forceinline__ f32x4 mfma16(s16x8 a, s16x8 b, f32x4 c){
  return __builtin_amdgcn_mfma_f32_16x16x32_bf16(a,b,c,0,0,0);
}
__device__ __forceinline__ f32x16 mfma32(s16x8 a, s16x8 b, f32x16 c){
  return __builtin_amdgcn_mfma_f32_32x32x16_bf16(a,b,c,0,0,0);
}

// ---------------------------------------------------------------------------
// dtype probe (validated rounds 2-10)
// ---------------------------------------------------------------------------
__global__ __launch_bounds__(256) void detect_dtype(const u16* __restrict__ x, u32* __restrict__ flag){
  __shared__ int cnt;
  if (threadIdx.x==0) cnt = 0;
  __syncthreads();
  int local = 0;
  for (int i = threadIdx.x; i < 4096; i += 256){
    u16 v = x[2*i];
    int e = (v>>7)&0xFF;
    if (e >= 140 || e <= 100) local++;
  }
  atomicAdd(&cnt, local);
  __syncthreads();
  if (threadIdx.x==0) *flag = (cnt > 1024) ? 1u : 0u;
}

struct CvtArgs { const void* src[10]; u16* dst[10]; int n[10]; };

__global__ __launch_bounds__(256) void convert_inputs(CvtArgs a, const u32* __restrict__ flag){
  const int which = blockIdx.y;
  const int n = a.n[which];
  const int base = blockIdx.x*2048 + threadIdx.x;
  if (base >= n) return;
  u16* dst = a.dst[which];
  if (*flag){
    const float* s = (const float*)a.src[which];
    #pragma unroll
    for (int j=0;j<8;j++){ int i = base + j*256; if (i<n) dst[i] = f2bf(s[i]); }
  } else {
    const u16* s = (const u16*)a.src[which];
    #pragma unroll
    for (int j=0;j<8;j++){ int i = base + j*256; if (i<n) dst[i] = s[i]; }
  }
}

// ---------------------------------------------------------------------------
// Fused convert+transpose of x: xT[b][c][s] = cvt(x[b][s][c]).  Grid (32,16,2).
// ---------------------------------------------------------------------------
__global__ __launch_bounds__(256) void transpose_x(
    const void* __restrict__ src, const u32* __restrict__ flag, u16* __restrict__ dst)
{
  __shared__ u16 T[64][72];
  const int s0 = blockIdx.x*64, c0 = blockIdx.y*64, b = blockIdx.z;
  const int t = threadIdx.x;
  const int r = t>>2, cc = (t&3)*16;
  const long off = ((long)(b*2048 + s0 + r))*1024 + c0 + cc;
  if (*flag){
    const float* p = (const float*)src + off;
    #pragma unroll
    for (int j=0;j<16;j++) T[r][cc+j] = f2bf(p[j]);
  } else {
    const u16* p = (const u16*)src + off;
    *(s16x8*)&T[r][cc]   = *(const s16x8*)p;
    *(s16x8*)&T[r][cc+8] = *(const s16x8*)(p+8);
  }
  __syncthreads();
  {
    const int orow = t&63, oc = (t>>6)*16;
    u16 tmp[16];
    #pragma unroll
    for (int j=0;j<16;j++) tmp[j] = T[oc+j][orow];
    u16* q = dst + (long)b*2097152 + (long)(c0+orow)*2048 + s0 + oc;
    *(s16x8*)q     = *(s16x8*)&tmp[0];
    *(s16x8*)(q+8) = *(s16x8*)&tmp[8];
  }
}

// sv partials from UNSCALED v inside qkv
__global__ __launch_bounds__(256) void rowsum_part(const u16* __restrict__ qkv, float* __restrict__ svp){
  const int c = blockIdx.x*256 + threadIdx.x;   // 0..2047 = b*1024 + cc
  const int b = c>>10, cc = c&1023;
  const int tz = blockIdx.y;
  const u16* p = qkv + ((long)(b*2048 + tz*256))*3072 + 2048 + cc;
  float s = 0.f;
  #pragma unroll 8
  for (int i=0;i<256;i++) s += bf2f(p[(long)i*3072]);
  svp[tz*2048 + c] = s;
}
__global__ __launch_bounds__(256) void rowsum_fin(const float* __restrict__ svp, float* __restrict__ sv){
  const int c = blockIdx.x*256 + threadIdx.x;
  float s = 0.f;
  #pragma unroll
  for (int z=0;z<8;z++) s += svp[z*2048 + c];
  sv[c] = s;
}

// ---------------------------------------------------------------------------
// NT GEMM, BM=128 x BN tile, BK=32, double-buffered LDS + global_load_lds(16B).
// (round-5/7 version — proven)
// ---------------------------------------------------------------------------
template<int BN, int BMODE, bool DYN, bool QS>
__global__ __launch_bounds__(256) void gemm_t(
    const u16* __restrict__ A, const u16* __restrict__ B,
    const u16* __restrict__ bias, const float* __restrict__ r1col,
    const u32* __restrict__ dflag, void* __restrict__ C,
    int K, int lda, int ldb, int ldc,
    long aBatch, long bBatch, long cBatch)
{
  constexpr int BM = 128;
  constexpr int ACH = BM/64, BCH = BN/64;
  constexpr int MI = (BN==128) ? 4 : 2;
  __shared__ u16 As[2][BM*32];
  __shared__ u16 Bs[2][BN*32];
  const int t = threadIdx.x, w = t>>6, quad = (t&63)>>4, l16 = t&15;
  const int z = blockIdx.z;
  const int m0 = blockIdx.x*BM, n0 = blockIdx.y*BN;
  const u16* Ag = A + (long)z*aBatch + (long)m0*lda;
  const u16* Bg = B + (long)z*bBatch + (long)n0*ldb;
  const int wm = (BN==128) ? (w>>1)*64 : w*32;
  const int wn = (BN==128) ? (w&1)*64 : 0;

  auto stage = [&](int buf, int k0){
    #pragma unroll
    for (int i=0;i<ACH;i++){
      const int chunk = i*256 + t;
      glds16(Ag + (long)(chunk>>2)*lda + k0 + (chunk&3)*8, &As[buf][(i*256 + w*64)*8]);
    }
    #pragma unroll
    for (int i=0;i<BCH;i++){
      const int chunk = i*256 + t;
      glds16(Bg + (long)(chunk>>2)*ldb + k0 + (chunk&3)*8, &Bs[buf][(i*256 + w*64)*8]);
    }
  };

  f32x4 acc[MI][4];
  #pragma unroll
  for (int i=0;i<MI;i++)
    #pragma unroll
    for (int j=0;j<4;j++) acc[i][j] = (f32x4){0.f,0.f,0.f,0.f};

  stage(0, 0);
  const int nk = K>>5;
  for (int kt=0; kt<nk; ++kt){
    __syncthreads();
    if (kt+1 < nk) stage((kt+1)&1, (kt+1)<<5);
    const u16* as = As[kt&1];
    const u16* bs = Bs[kt&1];
    s16x8 a[MI], bb[4];
    #pragma unroll
    for (int i=0;i<MI;i++) a[i] = *(const s16x8*)&as[(wm + i*16 + l16)*32 + quad*8];
    #pragma unroll
    for (int j=0;j<4;j++)  bb[j]= *(const s16x8*)&bs[(wn + j*16 + l16)*32 + quad*8];
    #pragma unroll
    for (int i=0;i<MI;i++)
      #pragma unroll
      for (int j=0;j<4;j++)
        acc[i][j] = mfma16(a[i], bb[j], acc[i][j]);
  }

  bool f32o = false;
  if (DYN) f32o = (*dflag != 0);
  #pragma unroll
  for (int i=0;i<MI;i++){
    #pragma unroll
    for (int j=0;j<4;j++){
      const int col = n0 + wn + j*16 + l16;
      #pragma unroll
      for (int r=0;r<4;r++){
        const int row = m0 + wm + i*16 + quad*4 + r;
        float vv = acc[i][j][r];
        if (BMODE==1) vv += bf2f(bias[row]);
        if (BMODE==2) vv += bf2f(bias[col]);
        if (BMODE==3) vv += bf2f(bias[row]) * r1col[z*1024 + col];
        if (QS){ if (col < 1024) vv *= SCL; }
        const long idx = (long)z*cBatch + (long)row*ldc + col;
        if (DYN && f32o) ((float*)C)[idx] = vv;
        else             ((u16*)C)[idx]   = f2bf(vv);
      }
    }
  }
}

// ---------------------------------------------------------------------------
// Fused softmax-denominator + V-scale-transpose (R9 version — proven).
// Pass 1: l[q] = sum_k exp2(q'.k).  Pass 2: VtG[b][h*64+c][q] = v/l[q] via Qs.
// ---------------------------------------------------------------------------
__global__ __launch_bounds__(256) void attn_stats(const u16* __restrict__ qkv, u16* __restrict__ VtG){
  __shared__ u16 Qs[64][68];
  __shared__ u16 Ks[64][68];
  __shared__ float red[2][64];
  __shared__ float ilv[64];
  const int q0 = blockIdx.x*64, bh = blockIdx.y, b = bh>>4, h = bh&15;
  const int t = threadIdx.x, w = t>>6, l32 = t&31, half = (t&63)>>5;
  const int wq = w>>1, wk = w&1;
  {
    const int r = t>>2, cc = (t&3)*16;
    const u16* p = &qkv[((long)(b*2048 + q0 + r))*3072 + h*64 + cc];
    *(s16x8*)&Qs[r][cc]   = *(const s16x8*)p;
    *(s16x8*)&Qs[r][cc+8] = *(const s16x8*)(p+8);
  }
  __syncthreads();
  s16x8 aq[4];
  #pragma unroll
  for (int u=0;u<4;u++) aq[u] = *(s16x8*)&Qs[wq*32 + l32][u*16 + half*8];
  float lp[16];
  #pragma unroll
  for (int r=0;r<16;r++) lp[r] = 0.f;

  for (int kc=0; kc<2048; kc+=64){
    __syncthreads();
    {
      const int r = t>>2, cc = (t&3)*16;
      const u16* p = &qkv[((long)(b*2048 + kc + r))*3072 + 1024 + h*64 + cc];
      *(s16x8*)&Ks[r][cc]   = *(const s16x8*)p;
      *(s16x8*)&Ks[r][cc+8] = *(const s16x8*)(p+8);
    }
    __syncthreads();
    s16x8 kb[4];
    #pragma unroll
    for (int u=0;u<4;u++) kb[u] = *(s16x8*)&Ks[wk*32 + l32][u*16 + half*8];
    f32x16 acc = {};
    #pragma unroll
    for (int u=0;u<4;u++) acc = mfma32(aq[u], kb[u], acc);
    #pragma unroll
    for (int r=0;r<16;r++) lp[r] += EXP2(acc[r]);
  }
  #pragma unroll
  for (int off=1; off<32; off<<=1)
    #pragma unroll
    for (int r=0;r<16;r++) lp[r] += __shfl_xor(lp[r], off);
  if (l32 == 0){
    #pragma unroll
    for (int r=0;r<16;r++)
      red[wk][wq*32 + 4*half + (r&3) + 8*(r>>2)] = lp[r];
  }
  __syncthreads();
  if (t < 64) ilv[t] = 1.f / (red[0][t] + red[1][t]);
  __syncthreads();
  // ---- fused V scale+transpose through Qs (dead after aq) ----
  {
    const int r = t>>2, cc = (t&3)*16;
    const u16* p = &qkv[((long)(b*2048 + q0 + r))*3072 + 2048 + h*64 + cc];
    const float sc = ilv[r];
    s16x8 v0 = *(const s16x8*)p, v1 = *(const s16x8*)(p+8);
    #pragma unroll
    for (int j=0;j<8;j++){
      Qs[r][cc+j]   = f2bf(bf2f((u16)v0[j])*sc);
      Qs[r][cc+8+j] = f2bf(bf2f((u16)v1[j])*sc);
    }
  }
  __syncthreads();
  {
    const int orow = t&63, oc = (t>>6)*16;
    u16 tmp[16];
    #pragma unroll
    for (int j=0;j<16;j++) tmp[j] = Qs[oc+j][orow];
    u16* q = VtG + (long)b*2097152 + (long)(h*64+orow)*2048 + q0 + oc;
    *(s16x8*)q     = *(s16x8*)&tmp[0];
    *(s16x8*)(q+8) = *(s16x8*)&tmp[8];
  }
}

// ---------------------------------------------------------------------------
// Mt[b, h*64+d, k] = sum_q exp2(q'.k) * vtilde[d,q]   (V pre-scaled by il[q]).
// R5/R7 3-barrier structure — the proven local optimum (68 µs, ~506 TF eff).
// LDS 34.8 KB -> 4 blocks/CU.  Grid (32, 32), block 256.
// ---------------------------------------------------------------------------
__global__ __launch_bounds__(256) void attn_pv(
    const u16* __restrict__ qkv, const u16* __restrict__ VtG, u16* __restrict__ Mt)
{
  __shared__ u16 Ks[64][68];
  __shared__ u16 Qs[64][68];
  __shared__ u16 Vs[64][68];
  __shared__ u16 Ps[64][68];
  const int k0 = blockIdx.x*64, bh = blockIdx.y, b = bh>>4, h = bh&15;
  const int t = threadIdx.x, w = t>>6, l32 = t&31, half = (t&63)>>5;
  const int wr = w>>1, wk = w&1;
  {
    const int r = t>>2, cc = (t&3)*16;
    const u16* p = &qkv[((long)(b*2048 + k0 + r))*3072 + 1024 + h*64 + cc];
    *(s16x8*)&Ks[r][cc]   = *(const s16x8*)p;
    *(s16x8*)&Ks[r][cc+8] = *(const s16x8*)(p+8);
  }
  __syncthreads();
  s16x8 kb[4];
  #pragma unroll
  for (int u=0;u<4;u++) kb[u] = *(s16x8*)&Ks[wk*32 + l32][u*16 + half*8];

  f32x16 accM = {};
  for (int q0=0; q0<2048; q0+=64){
    __syncthreads();                           // prev Ps/Qs/Vs reads done
    {
      const int r = t>>2, cc = (t&3)*16;
      const u16* pq = &qkv[((long)(b*2048 + q0 + r))*3072 + h*64 + cc];
      *(s16x8*)&Qs[r][cc]   = *(const s16x8*)pq;
      *(s16x8*)&Qs[r][cc+8] = *(const s16x8*)(pq+8);
      const u16* pv = &VtG[((long)(b*1024 + h*64 + r))*2048 + q0 + cc];
      *(s16x8*)&Vs[r][cc]   = *(const s16x8*)pv;
      *(s16x8*)&Vs[r][cc+8] = *(const s16x8*)(pv+8);
    }
    __syncthreads();
    s16x8 aq[4];
    #pragma unroll
    for (int u=0;u<4;u++) aq[u] = *(s16x8*)&Qs[wr*32 + l32][u*16 + half*8];
    f32x16 acc = {};
    #pragma unroll
    for (int u=0;u<4;u++) acc = mfma32(aq[u], kb[u], acc);
    const int kcol = wk*32 + l32;
    #pragma unroll
    for (int g=0; g<4; g++){
      float p0 = EXP2(acc[4*g+0]);
      float p1 = EXP2(acc[4*g+1]);
      float p2 = EXP2(acc[4*g+2]);
      float p3 = EXP2(acc[4*g+3]);
      u64 v = (u64)pkbf(p0,p1) | ((u64)pkbf(p2,p3) << 32);
      *(u64*)&Ps[kcol][wr*32 + 8*g + 4*half] = v;
    }
    __syncthreads();                           // Ps visible
    s16x8 av[4], bp[4];
    #pragma unroll
    for (int u=0;u<4;u++) av[u] = *(s16x8*)&Vs[wr*32 + l32][u*16 + half*8];
    #pragma unroll
    for (int u=0;u<4;u++) bp[u] = *(s16x8*)&Ps[wk*32 + l32][u*16 + half*8];
    #pragma unroll
    for (int u=0;u<4;u++) accM = mfma32(av[u], bp[u], accM);
  }
  #pragma unroll
  for (int r=0;r<16;r++){
    const int d = wr*32 + 4*half + (r&3) + 8*(r>>2);
    const int k = k0 + wk*32 + l32;
    Mt[((long)(b*1024 + h*64 + d))*2048 + k] = f2bf(accM[r]);
  }
}

extern "C" void kernel_launch(void* const* d_in, const int* in_sizes, int n_in,
                              void* d_out, int out_size, void* d_ws, size_t ws_size,
                              hipStream_t stream)
{
  (void)n_in; (void)out_size; (void)ws_size;
  char* ws = (char*)d_ws;
  u32*  dflag = (u32*)ws;            ws += 64;
  u16*  whc   = (u16*)ws;            ws += (size_t)8388608;
  u16*  wqkvc = (u16*)ws;            ws += (size_t)6291456;
  u16*  woc   = (u16*)ws;            ws += (size_t)8388608;
  u16*  bhc   = (u16*)ws;            ws += 4096;
  u16*  bqkvc = (u16*)ws;            ws += 8192;
  u16*  boc   = (u16*)ws;            ws += 4096;
  u16*  xT    = (u16*)ws;            ws += (size_t)8388608;
  u16*  xh    = (u16*)ws;            ws += (size_t)8388608;
  u16*  qkvb  = (u16*)ws;            ws += (size_t)25165824;
  u16*  VtG   = (u16*)ws;            ws += (size_t)8388608;
  u16*  Mt    = (u16*)ws;            ws += (size_t)8388608;
  float* svp  = (float*)ws;          ws += (size_t)65536;
  float* sv   = (float*)ws;          ws += 8192;

  // 0) probe dtype + canonicalize weight/bias inputs to bf16 (x handled by transpose_x)
  detect_dtype<<<1,256,0,stream>>>((const u16*)d_in[0], dflag);
  CvtArgs ca;
  const void* srcs[10] = {d_in[1], d_in[2], d_in[3], d_in[4], d_in[5],
                          d_in[6], d_in[7], d_in[8], d_in[9], d_in[10]};
  u16* dsts[10] = {whc, bhc, wqkvc, bqkvc, wqkvc+1048576, bqkvc+1024,
                   wqkvc+2097152, bqkvc+2048, woc, boc};
  const int ns[10] = {in_sizes[1], in_sizes[2], in_sizes[3], in_sizes[4], in_sizes[5],
                      in_sizes[6], in_sizes[7], in_sizes[8], in_sizes[9], in_sizes[10]};
  for (int i=0;i<10;i++){ ca.src[i]=srcs[i]; ca.dst[i]=dsts[i]; ca.n[i]=ns[i]; }
  convert_inputs<<<dim3(2048,10),256,0,stream>>>(ca, dflag);

  const long S2M = 2097152L;   // 2048*1024

  // 1) xT[b,c,s] = cvt(x[b,s,c])^T   (fused convert+transpose)
  transpose_x<<<dim3(32,16,2),256,0,stream>>>(d_in[0], dflag, xT);

  // 2) xh = w_hseq @ xT^T + b_hseq   (NT, row bias)
  gemm_t<64,1,false,false><<<dim3(16,16,2),256,0,stream>>>(whc, xT, bhc, nullptr, dflag, xh,
      2048, 2048, 2048, 1024, 0L, S2M, S2M);

  // 3) qkv = xh @ Wqkv^T + bqkv; q-columns pre-scaled by SCL   (NT, col bias)
  gemm_t<128,2,false,true><<<dim3(16,24,2),256,0,stream>>>(xh, wqkvc, bqkvc, nullptr, dflag, qkvb,
      1024, 1024, 1024, 3072, S2M, 0L, (long)2048*3072);

  // 4) sv[b,c] = sum_t v[b,t,c]
  rowsum_part<<<dim3(8,8),256,0,stream>>>(qkvb, svp);
  rowsum_fin<<<8,256,0,stream>>>(svp, sv);

  // 5) softmax denominators + fused V scale-transpose -> VtG
  attn_stats<<<dim3(32,32),256,0,stream>>>(qkvb, VtG);

  // 6) Mt = (attn^T @ v)^T   (R5/R7 proven structure)
  attn_pv<<<dim3(32,32),256,0,stream>>>(qkvb, VtG, Mt);

  // 7) out = w_oseq @ Mt^T + b_oseq (x) sv   (NT, rank-1 bias, dyn dtype)
  gemm_t<64,3,true,false><<<dim3(16,16,2),256,0,stream>>>(woc, Mt, boc, sv, dflag, d_out,
      2048, 2048, 2048, 1024, 0L, S2M, S2M);
}

// Round 12
// 342.362 us; speedup vs baseline: 1.1855x; 1.0086x over previous
//
#include <hip/hip_runtime.h>
#include <hip/hip_bf16.h>

typedef unsigned short u16;
typedef unsigned int u32;
typedef unsigned long long u64;
typedef __attribute__((ext_vector_type(8))) short s16x8;
typedef __attribute__((ext_vector_type(4))) float f32x4;
typedef __attribute__((ext_vector_type(16))) float f32x16;

#define SCL 0.1803368867f   // 0.125 * log2(e): exp(s/8) = 2^(s*SCL)

#if __has_builtin(__builtin_amdgcn_exp2f)
#define EXP2(x) __builtin_amdgcn_exp2f(x)
#else
#define EXP2(x) exp2f(x)
#endif

__device__ __forceinline__ float bf2f(u16 v){ u32 u = ((u32)v)<<16; return __builtin_bit_cast(float,u); }
__device__ __forceinline__ u16 f2bf(float f){
  u32 u = __builtin_bit_cast(u32,f);
  u += 0x7fff + ((u>>16)&1);
  return (u16)(u>>16);
}
__device__ __forceinline__ u32 pkbf(float a, float b){   // pack 2 bf16
  u32 ua = __builtin_bit_cast(u32,a) + 0x8000u;
  u32 ub = __builtin_bit_cast(u32,b) + 0x8000u;
  return (ua>>16) | (ub & 0xFFFF0000u);
}
// async global->LDS, 16B per lane; lds_u MUST be wave-uniform (HW adds lane*16)
__device__ __forceinline__ void glds16(const u16* g, const u16* lds_u){
  __builtin_amdgcn_global_load_lds(
      (const __attribute__((address_space(1))) void*)(u64)g,
      (__attribute__((address_space(3))) void*)(u32)(u64)lds_u,
      16, 0, 0);
}
__device__ __forceinline__ f32x4 mfma16(s16x8 a, s16x8 b, f32x4 c){
  return __builtin_amdgcn_mfma_f32_16x16x32_bf16(a,b,c,0,0,0);
}
__device__ __forceinline__ f32x16 mfma32(s16x8 a, s16x8 b, f32x16 c){
  return __builtin_amdgcn_mfma_f32_32x32x16_bf16(a,b,c,0,0,0);
}

// ---------------------------------------------------------------------------
// dtype probe (validated rounds 2-11)
// ---------------------------------------------------------------------------
__global__ __launch_bounds__(256) void detect_dtype(const u16* __restrict__ x, u32* __restrict__ flag){
  __shared__ int cnt;
  if (threadIdx.x==0) cnt = 0;
  __syncthreads();
  int local = 0;
  for (int i = threadIdx.x; i < 4096; i += 256){
    u16 v = x[2*i];
    int e = (v>>7)&0xFF;
    if (e >= 140 || e <= 100) local++;
  }
  atomicAdd(&cnt, local);
  __syncthreads();
  if (threadIdx.x==0) *flag = (cnt > 1024) ? 1u : 0u;
}

struct CvtArgs { const void* src[10]; u16* dst[10]; int n[10]; };

// ---------------------------------------------------------------------------
// Merged weight/bias convert (y<10) + x convert-transpose (y==10).
// Grid (2048, 11), block 256.
// ---------------------------------------------------------------------------
__global__ __launch_bounds__(256) void convert_all(
    CvtArgs a, const void* __restrict__ xsrc,
    const u32* __restrict__ flag, u16* __restrict__ xT)
{
  __shared__ u16 T[64][72];
  const int t = threadIdx.x;
  if (blockIdx.y < 10){
    const int which = blockIdx.y;
    const int n = a.n[which];
    const int base = blockIdx.x*2048 + t;
    if (base >= n) return;
    u16* dst = a.dst[which];
    if (*flag){
      const float* s = (const float*)a.src[which];
      #pragma unroll
      for (int j=0;j<8;j++){ int i = base + j*256; if (i<n) dst[i] = f2bf(s[i]); }
    } else {
      const u16* s = (const u16*)a.src[which];
      #pragma unroll
      for (int j=0;j<8;j++){ int i = base + j*256; if (i<n) dst[i] = s[i]; }
    }
    return;
  }
  // ---- x transpose: xT[b][c][s] = cvt(x[b][s][c]) ----
  const int bx = blockIdx.x;
  if (bx >= 1024) return;
  const int s0 = (bx&31)*64, c0 = ((bx>>5)&15)*64, b = bx>>9;
  const int r = t>>2, cc = (t&3)*16;
  const long off = ((long)(b*2048 + s0 + r))*1024 + c0 + cc;
  if (*flag){
    const float* p = (const float*)xsrc + off;
    #pragma unroll
    for (int j=0;j<16;j++) T[r][cc+j] = f2bf(p[j]);
  } else {
    const u16* p = (const u16*)xsrc + off;
    *(s16x8*)&T[r][cc]   = *(const s16x8*)p;
    *(s16x8*)&T[r][cc+8] = *(const s16x8*)(p+8);
  }
  __syncthreads();
  {
    const int orow = t&63, oc = (t>>6)*16;
    u16 tmp[16];
    #pragma unroll
    for (int j=0;j<16;j++) tmp[j] = T[oc+j][orow];
    u16* q = xT + (long)b*2097152 + (long)(c0+orow)*2048 + s0 + oc;
    *(s16x8*)q     = *(s16x8*)&tmp[0];
    *(s16x8*)(q+8) = *(s16x8*)&tmp[8];
  }
}

// ---------------------------------------------------------------------------
// sv[row] = sum_k Mt[row][k]  (softmax rows sum to 1 => equals sum_t v[b,t,c]).
// Grid 512, block 256 (4 waves, 1 Mt-row each).
// ---------------------------------------------------------------------------
__global__ __launch_bounds__(256) void rowsum_mt(const u16* __restrict__ Mt, float* __restrict__ sv){
  const int row = blockIdx.x*4 + (threadIdx.x>>6);
  const int lane = threadIdx.x&63;
  const u16* p = Mt + (long)row*2048;
  float s = 0.f;
  #pragma unroll
  for (int i=0;i<4;i++){
    s16x8 v = *(const s16x8*)&p[i*512 + lane*8];
    #pragma unroll
    for (int j=0;j<8;j++) s += bf2f((u16)v[j]);
  }
  #pragma unroll
  for (int off=32; off>=1; off>>=1) s += __shfl_xor(s, off);
  if (lane==0) sv[row] = s;
}

// ---------------------------------------------------------------------------
// NT GEMM, BM=128 x BN tile, BK=32, double-buffered LDS + global_load_lds(16B).
// (round-5/7 version — proven)
// ---------------------------------------------------------------------------
template<int BN, int BMODE, bool DYN, bool QS>
__global__ __launch_bounds__(256) void gemm_t(
    const u16* __restrict__ A, const u16* __restrict__ B,
    const u16* __restrict__ bias, const float* __restrict__ r1col,
    const u32* __restrict__ dflag, void* __restrict__ C,
    int K, int lda, int ldb, int ldc,
    long aBatch, long bBatch, long cBatch)
{
  constexpr int BM = 128;
  constexpr int ACH = BM/64, BCH = BN/64;
  constexpr int MI = (BN==128) ? 4 : 2;
  __shared__ u16 As[2][BM*32];
  __shared__ u16 Bs[2][BN*32];
  const int t = threadIdx.x, w = t>>6, quad = (t&63)>>4, l16 = t&15;
  const int z = blockIdx.z;
  const int m0 = blockIdx.x*BM, n0 = blockIdx.y*BN;
  const u16* Ag = A + (long)z*aBatch + (long)m0*lda;
  const u16* Bg = B + (long)z*bBatch + (long)n0*ldb;
  const int wm = (BN==128) ? (w>>1)*64 : w*32;
  const int wn = (BN==128) ? (w&1)*64 : 0;

  auto stage = [&](int buf, int k0){
    #pragma unroll
    for (int i=0;i<ACH;i++){
      const int chunk = i*256 + t;
      glds16(Ag + (long)(chunk>>2)*lda + k0 + (chunk&3)*8, &As[buf][(i*256 + w*64)*8]);
    }
    #pragma unroll
    for (int i=0;i<BCH;i++){
      const int chunk = i*256 + t;
      glds16(Bg + (long)(chunk>>2)*ldb + k0 + (chunk&3)*8, &Bs[buf][(i*256 + w*64)*8]);
    }
  };

  f32x4 acc[MI][4];
  #pragma unroll
  for (int i=0;i<MI;i++)
    #pragma unroll
    for (int j=0;j<4;j++) acc[i][j] = (f32x4){0.f,0.f,0.f,0.f};

  stage(0, 0);
  const int nk = K>>5;
  for (int kt=0; kt<nk; ++kt){
    __syncthreads();
    if (kt+1 < nk) stage((kt+1)&1, (kt+1)<<5);
    const u16* as = As[kt&1];
    const u16* bs = Bs[kt&1];
    s16x8 a[MI], bb[4];
    #pragma unroll
    for (int i=0;i<MI;i++) a[i] = *(const s16x8*)&as[(wm + i*16 + l16)*32 + quad*8];
    #pragma unroll
    for (int j=0;j<4;j++)  bb[j]= *(const s16x8*)&bs[(wn + j*16 + l16)*32 + quad*8];
    #pragma unroll
    for (int i=0;i<MI;i++)
      #pragma unroll
      for (int j=0;j<4;j++)
        acc[i][j] = mfma16(a[i], bb[j], acc[i][j]);
  }

  bool f32o = false;
  if (DYN) f32o = (*dflag != 0);
  #pragma unroll
  for (int i=0;i<MI;i++){
    #pragma unroll
    for (int j=0;j<4;j++){
      const int col = n0 + wn + j*16 + l16;
      #pragma unroll
      for (int r=0;r<4;r++){
        const int row = m0 + wm + i*16 + quad*4 + r;
        float vv = acc[i][j][r];
        if (BMODE==1) vv += bf2f(bias[row]);
        if (BMODE==2) vv += bf2f(bias[col]);
        if (BMODE==3) vv += bf2f(bias[row]) * r1col[z*1024 + col];
        if (QS){ if (col < 1024) vv *= SCL; }
        const long idx = (long)z*cBatch + (long)row*ldc + col;
        if (DYN && f32o) ((float*)C)[idx] = vv;
        else             ((u16*)C)[idx]   = f2bf(vv);
      }
    }
  }
}

// ---------------------------------------------------------------------------
// Fused softmax-denominator + V-scale-transpose (R9 version — proven).
// Pass 1: l[q] = sum_k exp2(q'.k).  Pass 2: VtG[b][h*64+c][q] = v/l[q] via Qs.
// ---------------------------------------------------------------------------
__global__ __launch_bounds__(256) void attn_stats(const u16* __restrict__ qkv, u16* __restrict__ VtG){
  __shared__ u16 Qs[64][68];
  __shared__ u16 Ks[64][68];
  __shared__ float red[2][64];
  __shared__ float ilv[64];
  const int q0 = blockIdx.x*64, bh = blockIdx.y, b = bh>>4, h = bh&15;
  const int t = threadIdx.x, w = t>>6, l32 = t&31, half = (t&63)>>5;
  const int wq = w>>1, wk = w&1;
  {
    const int r = t>>2, cc = (t&3)*16;
    const u16* p = &qkv[((long)(b*2048 + q0 + r))*3072 + h*64 + cc];
    *(s16x8*)&Qs[r][cc]   = *(const s16x8*)p;
    *(s16x8*)&Qs[r][cc+8] = *(const s16x8*)(p+8);
  }
  __syncthreads();
  s16x8 aq[4];
  #pragma unroll
  for (int u=0;u<4;u++) aq[u] = *(s16x8*)&Qs[wq*32 + l32][u*16 + half*8];
  float lp[16];
  #pragma unroll
  for (int r=0;r<16;r++) lp[r] = 0.f;

  for (int kc=0; kc<2048; kc+=64){
    __syncthreads();
    {
      const int r = t>>2, cc = (t&3)*16;
      const u16* p = &qkv[((long)(b*2048 + kc + r))*3072 + 1024 + h*64 + cc];
      *(s16x8*)&Ks[r][cc]   = *(const s16x8*)p;
      *(s16x8*)&Ks[r][cc+8] = *(const s16x8*)(p+8);
    }
    __syncthreads();
    s16x8 kb[4];
    #pragma unroll
    for (int u=0;u<4;u++) kb[u] = *(s16x8*)&Ks[wk*32 + l32][u*16 + half*8];
    f32x16 acc = {};
    #pragma unroll
    for (int u=0;u<4;u++) acc = mfma32(aq[u], kb[u], acc);
    #pragma unroll
    for (int r=0;r<16;r++) lp[r] += EXP2(acc[r]);
  }
  #pragma unroll
  for (int off=1; off<32; off<<=1)
    #pragma unroll
    for (int r=0;r<16;r++) lp[r] += __shfl_xor(lp[r], off);
  if (l32 == 0){
    #pragma unroll
    for (int r=0;r<16;r++)
      red[wk][wq*32 + 4*half + (r&3) + 8*(r>>2)] = lp[r];
  }
  __syncthreads();
  if (t < 64) ilv[t] = 1.f / (red[0][t] + red[1][t]);
  __syncthreads();
  // ---- fused V scale+transpose through Qs (dead after aq) ----
  {
    const int r = t>>2, cc = (t&3)*16;
    const u16* p = &qkv[((long)(b*2048 + q0 + r))*3072 + 2048 + h*64 + cc];
    const float sc = ilv[r];
    s16x8 v0 = *(const s16x8*)p, v1 = *(const s16x8*)(p+8);
    #pragma unroll
    for (int j=0;j<8;j++){
      Qs[r][cc+j]   = f2bf(bf2f((u16)v0[j])*sc);
      Qs[r][cc+8+j] = f2bf(bf2f((u16)v1[j])*sc);
    }
  }
  __syncthreads();
  {
    const int orow = t&63, oc = (t>>6)*16;
    u16 tmp[16];
    #pragma unroll
    for (int j=0;j<16;j++) tmp[j] = Qs[oc+j][orow];
    u16* q = VtG + (long)b*2097152 + (long)(h*64+orow)*2048 + q0 + oc;
    *(s16x8*)q     = *(s16x8*)&tmp[0];
    *(s16x8*)(q+8) = *(s16x8*)&tmp[8];
  }
}

// ---------------------------------------------------------------------------
// Mt[b, h*64+d, k] = sum_q exp2(q'.k) * vtilde[d,q]   (V pre-scaled by il[q]).
// R5/R7 3-barrier structure — the proven local optimum (68 µs).
// LDS 34.8 KB -> 4 blocks/CU.  Grid (32, 32), block 256.
// ---------------------------------------------------------------------------
__global__ __launch_bounds__(256) void attn_pv(
    const u16* __restrict__ qkv, const u16* __restrict__ VtG, u16* __restrict__ Mt)
{
  __shared__ u16 Ks[64][68];
  __shared__ u16 Qs[64][68];
  __shared__ u16 Vs[64][68];
  __shared__ u16 Ps[64][68];
  const int k0 = blockIdx.x*64, bh = blockIdx.y, b = bh>>4, h = bh&15;
  const int t = threadIdx.x, w = t>>6, l32 = t&31, half = (t&63)>>5;
  const int wr = w>>1, wk = w&1;
  {
    const int r = t>>2, cc = (t&3)*16;
    const u16* p = &qkv[((long)(b*2048 + k0 + r))*3072 + 1024 + h*64 + cc];
    *(s16x8*)&Ks[r][cc]   = *(const s16x8*)p;
    *(s16x8*)&Ks[r][cc+8] = *(const s16x8*)(p+8);
  }
  __syncthreads();
  s16x8 kb[4];
  #pragma unroll
  for (int u=0;u<4;u++) kb[u] = *(s16x8*)&Ks[wk*32 + l32][u*16 + half*8];

  f32x16 accM = {};
  for (int q0=0; q0<2048; q0+=64){
    __syncthreads();                           // prev Ps/Qs/Vs reads done
    {
      const int r = t>>2, cc = (t&3)*16;
      const u16* pq = &qkv[((long)(b*2048 + q0 + r))*3072 + h*64 + cc];
      *(s16x8*)&Qs[r][cc]   = *(const s16x8*)pq;
      *(s16x8*)&Qs[r][cc+8] = *(const s16x8*)(pq+8);
      const u16* pv = &VtG[((long)(b*1024 + h*64 + r))*2048 + q0 + cc];
      *(s16x8*)&Vs[r][cc]   = *(const s16x8*)pv;
      *(s16x8*)&Vs[r][cc+8] = *(const s16x8*)(pv+8);
    }
    __syncthreads();
    s16x8 aq[4];
    #pragma unroll
    for (int u=0;u<4;u++) aq[u] = *(s16x8*)&Qs[wr*32 + l32][u*16 + half*8];
    f32x16 acc = {};
    #pragma unroll
    for (int u=0;u<4;u++) acc = mfma32(aq[u], kb[u], acc);
    const int kcol = wk*32 + l32;
    #pragma unroll
    for (int g=0; g<4; g++){
      float p0 = EXP2(acc[4*g+0]);
      float p1 = EXP2(acc[4*g+1]);
      float p2 = EXP2(acc[4*g+2]);
      float p3 = EXP2(acc[4*g+3]);
      u64 v = (u64)pkbf(p0,p1) | ((u64)pkbf(p2,p3) << 32);
      *(u64*)&Ps[kcol][wr*32 + 8*g + 4*half] = v;
    }
    __syncthreads();                           // Ps visible
    s16x8 av[4], bp[4];
    #pragma unroll
    for (int u=0;u<4;u++) av[u] = *(s16x8*)&Vs[wr*32 + l32][u*16 + half*8];
    #pragma unroll
    for (int u=0;u<4;u++) bp[u] = *(s16x8*)&Ps[wk*32 + l32][u*16 + half*8];
    #pragma unroll
    for (int u=0;u<4;u++) accM = mfma32(av[u], bp[u], accM);
  }
  #pragma unroll
  for (int r=0;r<16;r++){
    const int d = wr*32 + 4*half + (r&3) + 8*(r>>2);
    const int k = k0 + wk*32 + l32;
    Mt[((long)(b*1024 + h*64 + d))*2048 + k] = f2bf(accM[r]);
  }
}

extern "C" void kernel_launch(void* const* d_in, const int* in_sizes, int n_in,
                              void* d_out, int out_size, void* d_ws, size_t ws_size,
                              hipStream_t stream)
{
  (void)n_in; (void)out_size; (void)ws_size;
  char* ws = (char*)d_ws;
  u32*  dflag = (u32*)ws;            ws += 64;
  u16*  whc   = (u16*)ws;            ws += (size_t)8388608;
  u16*  wqkvc = (u16*)ws;            ws += (size_t)6291456;
  u16*  woc   = (u16*)ws;            ws += (size_t)8388608;
  u16*  bhc   = (u16*)ws;            ws += 4096;
  u16*  bqkvc = (u16*)ws;            ws += 8192;
  u16*  boc   = (u16*)ws;            ws += 4096;
  u16*  xT    = (u16*)ws;            ws += (size_t)8388608;
  u16*  xh    = (u16*)ws;            ws += (size_t)8388608;
  u16*  qkvb  = (u16*)ws;            ws += (size_t)25165824;
  u16*  VtG   = (u16*)ws;            ws += (size_t)8388608;
  u16*  Mt    = (u16*)ws;            ws += (size_t)8388608;
  float* sv   = (float*)ws;          ws += 8192;

  // 0) probe dtype + canonicalize all inputs (weights/biases + x-transpose fused)
  detect_dtype<<<1,256,0,stream>>>((const u16*)d_in[0], dflag);
  CvtArgs ca;
  const void* srcs[10] = {d_in[1], d_in[2], d_in[3], d_in[4], d_in[5],
                          d_in[6], d_in[7], d_in[8], d_in[9], d_in[10]};
  u16* dsts[10] = {whc, bhc, wqkvc, bqkvc, wqkvc+1048576, bqkvc+1024,
                   wqkvc+2097152, bqkvc+2048, woc, boc};
  const int ns[10] = {in_sizes[1], in_sizes[2], in_sizes[3], in_sizes[4], in_sizes[5],
                      in_sizes[6], in_sizes[7], in_sizes[8], in_sizes[9], in_sizes[10]};
  for (int i=0;i<10;i++){ ca.src[i]=srcs[i]; ca.dst[i]=dsts[i]; ca.n[i]=ns[i]; }
  convert_all<<<dim3(2048,11),256,0,stream>>>(ca, d_in[0], dflag, xT);

  const long S2M = 2097152L;   // 2048*1024

  // 1) xh = w_hseq @ xT^T + b_hseq   (NT, row bias)
  gemm_t<64,1,false,false><<<dim3(16,16,2),256,0,stream>>>(whc, xT, bhc, nullptr, dflag, xh,
      2048, 2048, 2048, 1024, 0L, S2M, S2M);

  // 2) qkv = xh @ Wqkv^T + bqkv; q-columns pre-scaled by SCL   (NT, col bias)
  gemm_t<128,2,false,true><<<dim3(16,24,2),256,0,stream>>>(xh, wqkvc, bqkvc, nullptr, dflag, qkvb,
      1024, 1024, 1024, 3072, S2M, 0L, (long)2048*3072);

  // 3) softmax denominators + fused V scale-transpose -> VtG
  attn_stats<<<dim3(32,32),256,0,stream>>>(qkvb, VtG);

  // 4) Mt = (attn^T @ v)^T   (R5/R7 proven structure)
  attn_pv<<<dim3(32,32),256,0,stream>>>(qkvb, VtG, Mt);

  // 5) sv[b,c] = sum_k Mt[b,c,k]  (softmax rows sum to 1 => = sum_t v[b,t,c])
  rowsum_mt<<<512,256,0,stream>>>(Mt, sv);

  // 6) out = w_oseq @ Mt^T + b_oseq (x) sv   (NT, rank-1 bias, dyn dtype)
  gemm_t<64,3,true,false><<<dim3(16,16,2),256,0,stream>>>(woc, Mt, boc, sv, dflag, d_out,
      2048, 2048, 2048, 1024, 0L, S2M, S2M);
}